// Round 3
// baseline (10264.305 us; speedup 1.0000x reference)
//
#include <hip/hip_runtime.h>
#include <hip/hip_bf16.h>
#include <math.h>

typedef __hip_bfloat16 bf16;

#define B_    256
#define SEQ_  200
#define H_    256
#define FREQ_ 9
#define NSEG_ 26

// MODE 0: external tensors are bf16. MODE 1: external tensors are fp32.
template<int MODE> __device__ __forceinline__ float ldin(const void* p, int i){
  if constexpr(MODE==0) return __bfloat162float(((const bf16*)p)[i]);
  else                  return ((const float*)p)[i];
}
template<int MODE> __device__ __forceinline__ void stout(void* p, int i, float v){
  if constexpr(MODE==0) ((bf16*)p)[i] = __float2bfloat16(v);
  else                  ((float*)p)[i] = v;
}
__device__ __forceinline__ float ldb(const bf16* p, int i){ return __bfloat162float(p[i]); }
__device__ __forceinline__ void stb(bf16* p, int i, float v){ p[i] = __float2bfloat16(v); }
__device__ __forceinline__ float gelu_(float x){ return 0.5f*x*(1.0f+erff(x*0.7071067811865475f)); }

// cos(m*pi/8), sin(m*pi/8), m=0..15
__device__ __constant__ float CT16[16] = {
  1.0f, 0.9238795325f, 0.7071067812f, 0.3826834324f, 0.0f, -0.3826834324f, -0.7071067812f, -0.9238795325f,
 -1.0f,-0.9238795325f,-0.7071067812f,-0.3826834324f, 0.0f,  0.3826834324f, 0.7071067812f,  0.9238795325f};
__device__ __constant__ float ST16[16] = {
  0.0f, 0.3826834324f, 0.7071067812f, 0.9238795325f, 1.0f,  0.9238795325f, 0.7071067812f,  0.3826834324f,
  0.0f,-0.3826834324f,-0.7071067812f,-0.9238795325f,-1.0f, -0.9238795325f,-0.7071067812f, -0.3826834324f};

// ---------------- dtype detector ----------------
// If inputs are fp32, even ushort indices are fp32 low-halves (random bits):
// ~25% have bf16-exponent e==0xFF or e<64. If inputs are bf16 (N(0,1)-scaled
// data), such exponents essentially never occur.
__global__ __launch_bounds__(256) void k_detect(const unsigned short* __restrict__ u,
                                                int* __restrict__ flag){
  int t = threadIdx.x;
  int cnt = 0;
  for(int i=t; i<2048; i+=256){
    unsigned short v = u[2*i];
    int e = (v >> 7) & 0xFF;
    if(e == 0xFF || e < 64) cnt++;
  }
  __shared__ int red[256];
  red[t] = cnt; __syncthreads();
  for(int off=128; off>0; off>>=1){ if(t<off) red[t]+=red[t+off]; __syncthreads(); }
  if(t==0) *flag = (red[0] > 64) ? 1 : 0;
}

// ---------------- Kernel 1: STFT ----------------
template<int MODE>
__global__ __launch_bounds__(256) void k_stft(const int* __restrict__ mf,
                                              const void* __restrict__ inp,
                                              bf16* __restrict__ sR, bf16* __restrict__ sI){
  if(*mf != MODE) return;
  int blk = blockIdx.x; int b = blk / NSEG_; int s = blk % NSEG_; int h = threadIdx.x;
  float xv[16];
  int t0 = s*8 - 8;
  #pragma unroll
  for(int k=0;k<16;k++){
    int t = t0 + k;
    xv[k] = (t>=0 && t<SEQ_) ? ldin<MODE>(inp, (b*SEQ_+t)*H_ + h) : 0.0f;
  }
  #pragma unroll
  for(int f=0;f<FREQ_;f++){
    float ar=0.f, ai=0.f;
    #pragma unroll
    for(int k=0;k<16;k++){
      int m = (f*k) & 15;
      ar += xv[k]*CT16[m];
      ai -= xv[k]*ST16[m];
    }
    int idx = ((b*NSEG_+s)*FREQ_+f)*H_ + h;
    stb(sR, idx, 0.25f*ar);
    stb(sI, idx, 0.25f*ai);
  }
}

// ---------------- Kernel 2: gating weight w[b,s] ----------------
template<int MODE>
__global__ __launch_bounds__(256) void k_w(const int* __restrict__ mf,
                                           const bf16* __restrict__ sR, const bf16* __restrict__ sI,
                                           const void* __restrict__ cw, const void* __restrict__ cb,
                                           float* __restrict__ wout){
  if(*mf != MODE) return;
  int blk = blockIdx.x; int b = blk / NSEG_; int s = blk % NSEG_; int h = threadIdx.x;
  float acc = 0.f;
  #pragma unroll
  for(int f=0;f<FREQ_;f++){
    int idx = ((b*NSEG_+s)*FREQ_+f)*H_ + h;
    float r = ldb(sR, idx), i = ldb(sI, idx);
    acc += sqrtf(r*r + i*i) * ldin<MODE>(cw, (s*H_+h)*FREQ_ + f);
  }
  __shared__ float red[256];
  red[h] = acc; __syncthreads();
  for(int off=128; off>0; off>>=1){ if(h<off) red[h] += red[h+off]; __syncthreads(); }
  if(h==0) wout[b*NSEG_+s] = red[0] + ldin<MODE>(cb, s) + __expf((float)(s - (NSEG_-1)));
}

// ---------------- Kernel 3: frequency mixer (9->18->9) ----------------
// in: spec [b][s][f][h] (scaled by w on load). out: [s][b][f][h]
template<int MODE>
__global__ __launch_bounds__(256) void k_fm(const int* __restrict__ mf,
                                            const bf16* __restrict__ sR, const bf16* __restrict__ sI,
                                            const float* __restrict__ wv_,
                                            const void* __restrict__ w1, const void* __restrict__ bb1,
                                            const void* __restrict__ w2, const void* __restrict__ bb2,
                                            bf16* __restrict__ oR, bf16* __restrict__ oI){
  if(*mf != MODE) return;
  int blk = blockIdx.x; int b = blk / NSEG_; int s = blk % NSEG_; int h = threadIdx.x;
  __shared__ float2 lw1[162], lw2[162], lb1[18], lb2[9];
  for(int i=threadIdx.x; i<162; i+=256){
    lw1[i] = make_float2(ldin<MODE>(w1, s*162+i), ldin<MODE>(w1, 4212 + s*162+i));
    lw2[i] = make_float2(ldin<MODE>(w2, s*162+i), ldin<MODE>(w2, 4212 + s*162+i));
  }
  if(threadIdx.x < 18) lb1[threadIdx.x] = make_float2(ldin<MODE>(bb1, s*18+threadIdx.x), ldin<MODE>(bb1, 468 + s*18+threadIdx.x));
  if(threadIdx.x < 9)  lb2[threadIdx.x] = make_float2(ldin<MODE>(bb2, s*9+threadIdx.x),  ldin<MODE>(bb2, 234 + s*9+threadIdx.x));
  __syncthreads();

  float wv = wv_[b*NSEG_+s];
  float xr[9], xi[9];
  #pragma unroll
  for(int f=0;f<9;f++){
    int idx = ((b*NSEG_+s)*FREQ_+f)*H_ + h;
    xr[f] = ldb(sR, idx)*wv; xi[f] = ldb(sI, idx)*wv;
  }
  float gr[18], gi[18];
  #pragma unroll
  for(int j=0;j<18;j++){
    float hr = lb1[j].x, hi = lb1[j].y;
    #pragma unroll
    for(int f=0;f<9;f++){
      float2 ww = lw1[f*18+j];
      hr += xr[f]*ww.x - xi[f]*ww.y;
      hi += xi[f]*ww.x + xr[f]*ww.y;
    }
    gr[j] = gelu_(hr); gi[j] = gelu_(hi);
  }
  #pragma unroll
  for(int f=0;f<9;f++){
    float orr = lb2[f].x, oii = lb2[f].y;
    #pragma unroll
    for(int j=0;j<18;j++){
      float2 ww = lw2[j*9+f];
      orr += gr[j]*ww.x - gi[j]*ww.y;
      oii += gi[j]*ww.x + gi[j]*ww.y;   // reference bug: o2i uses o1i with BOTH w2[0] and w2[1]
    }
    int o = ((s*B_+b)*FREQ_+f)*H_ + h;
    stb(oR, o, orr); stb(oI, o, oii);
  }
}

// ---------------- Kernel 4: channel mixer (256->512->256) ----------------
// grid = 26*288 (s-major). in [s][row][h], row=(b*9+f); out [row][s][h]
template<int MODE>
__global__ __launch_bounds__(256) void k_cm(const int* __restrict__ mf,
                                            const bf16* __restrict__ iR, const bf16* __restrict__ iI,
                                            const void* __restrict__ w1, const void* __restrict__ bb1,
                                            const void* __restrict__ w2, const void* __restrict__ bb2,
                                            bf16* __restrict__ oR, bf16* __restrict__ oI){
  if(*mf != MODE) return;
  int s = blockIdx.x / 288; int g = blockIdx.x % 288; int t = threadIdx.x;
  __shared__ float2 xx[8][256];
  __shared__ float2 hh[8][512];
  int row0 = g*8;
  for(int r=0;r<8;r++){
    int idx = (s*2304 + row0 + r)*256 + t;
    xx[r][t] = make_float2(ldb(iR, idx), ldb(iI, idx));
  }
  __syncthreads();
  float a0r[8], a0i[8], a1r[8], a1i[8];
  {
    float b0r = ldin<MODE>(bb1, s*512 + t),       b0i = ldin<MODE>(bb1, 13312 + s*512 + t);
    float b1r = ldin<MODE>(bb1, s*512 + t + 256), b1i = ldin<MODE>(bb1, 13312 + s*512 + t + 256);
    #pragma unroll
    for(int r=0;r<8;r++){ a0r[r]=b0r; a0i[r]=b0i; a1r[r]=b1r; a1i[r]=b1i; }
  }
  for(int h=0; h<256; h++){
    int base = (s*256 + h)*512;
    float w10a = ldin<MODE>(w1, base + t);
    float w10b = ldin<MODE>(w1, base + t + 256);
    float w11a = ldin<MODE>(w1, 3407872 + base + t);
    float w11b = ldin<MODE>(w1, 3407872 + base + t + 256);
    #pragma unroll
    for(int r=0;r<8;r++){
      float2 x = xx[r][h];
      a0r[r] += x.x*w10a - x.y*w11a;
      a0i[r] += x.y*w10a + x.x*w11a;
      a1r[r] += x.x*w10b - x.y*w11b;
      a1i[r] += x.y*w10b + x.x*w11b;
    }
  }
  #pragma unroll
  for(int r=0;r<8;r++){
    hh[r][t]     = make_float2(gelu_(a0r[r]), gelu_(a0i[r]));
    hh[r][t+256] = make_float2(gelu_(a1r[r]), gelu_(a1i[r]));
  }
  __syncthreads();
  float o_r[8], o_i[8];
  {
    float br = ldin<MODE>(bb2, s*256 + t), bi = ldin<MODE>(bb2, 6656 + s*256 + t);
    #pragma unroll
    for(int r=0;r<8;r++){ o_r[r]=br; o_i[r]=bi; }
  }
  for(int j=0; j<512; j++){
    int base = (s*512 + j)*256;
    float w20 = ldin<MODE>(w2, base + t);
    float w21 = ldin<MODE>(w2, 3407872 + base + t);
    float w2s = w20 + w21;
    #pragma unroll
    for(int r=0;r<8;r++){
      float2 hv = hh[r][j];
      o_r[r] += hv.x*w20 - hv.y*w21;
      o_i[r] += hv.y*w2s;             // reference bug replicated
    }
  }
  for(int r=0;r<8;r++){
    int o = ((row0 + r)*NSEG_ + s)*256 + t;
    stb(oR, o, o_r[r]); stb(oI, o, o_i[r]);
  }
}

// ---------------- Kernel 5: segment mixer (26->52->26) ----------------
template<int MODE>
__global__ __launch_bounds__(256) void k_sm(const int* __restrict__ mf,
                                            const bf16* __restrict__ iR, const bf16* __restrict__ iI,
                                            const void* __restrict__ w1, const void* __restrict__ bb1,
                                            const void* __restrict__ w2, const void* __restrict__ bb2,
                                            bf16* __restrict__ oR, bf16* __restrict__ oI){
  if(*mf != MODE) return;
  int bq = blockIdx.x / FREQ_; int f = blockIdx.x % FREQ_; int h = threadIdx.x;
  __shared__ float2 lw1[1352];  // [s*52+j] = (w10, w11)
  __shared__ float2 lw2[1352];  // [j*26+so] = (w20, w21)
  __shared__ float2 lb1[52], lb2[26];
  for(int i=threadIdx.x; i<1352; i+=256){
    lw1[i] = make_float2(ldin<MODE>(w1, f*1352+i), ldin<MODE>(w1, 12168 + f*1352+i));
    lw2[i] = make_float2(ldin<MODE>(w2, f*1352+i), ldin<MODE>(w2, 12168 + f*1352+i));
  }
  if(threadIdx.x < 52) lb1[threadIdx.x] = make_float2(ldin<MODE>(bb1, f*52+threadIdx.x), ldin<MODE>(bb1, 468 + f*52+threadIdx.x));
  if(threadIdx.x < 26) lb2[threadIdx.x] = make_float2(ldin<MODE>(bb2, f*26+threadIdx.x), ldin<MODE>(bb2, 234 + f*26+threadIdx.x));
  __syncthreads();

  int rbase = (bq*FREQ_+f)*NSEG_;
  float xr[26], xi[26];
  #pragma unroll
  for(int s=0;s<26;s++){
    int idx = (rbase + s)*256 + h;
    xr[s] = ldb(iR, idx); xi[s] = ldb(iI, idx);
  }
  float o_r[26], o_i[26];
  #pragma unroll
  for(int so=0;so<26;so++){ o_r[so] = lb2[so].x; o_i[so] = lb2[so].y; }
  #pragma unroll
  for(int j=0;j<52;j++){
    float hr = lb1[j].x, hi = lb1[j].y;
    #pragma unroll
    for(int s=0;s<26;s++){
      float2 ww = lw1[s*52+j];
      hr += xr[s]*ww.x - xi[s]*ww.y;
      hi += xi[s]*ww.x + xr[s]*ww.y;
    }
    hr = gelu_(hr); hi = gelu_(hi);
    #pragma unroll
    for(int so=0;so<26;so++){
      float2 ww = lw2[j*26+so];
      o_r[so] += hr*ww.x - hi*ww.y;
      o_i[so] += hi*(ww.x + ww.y);   // reference bug replicated
    }
  }
  #pragma unroll
  for(int so=0;so<26;so++){
    int o = (rbase + so)*256 + h;
    stb(oR, o, o_r[so]); stb(oI, o, o_i[so]);
  }
}

// ---------------- Kernel 6: iSTFT + residual + LayerNorm ----------------
template<int MODE>
__global__ __launch_bounds__(256) void k_ist(const int* __restrict__ mf,
                                             const bf16* __restrict__ iR, const bf16* __restrict__ iI,
                                             const void* __restrict__ inp,
                                             const void* __restrict__ lnw, const void* __restrict__ lnb,
                                             float* __restrict__ hs){
  if(*mf != MODE) return;
  int blk = blockIdx.x; int b = blk / SEQ_; int t = blk % SEQ_; int h = threadIdx.x;
  int l = t + 8;
  int s2 = l >> 3, k2 = l & 7;
  int s1 = s2 - 1, k1 = k2 + 8;
  float acc = 0.f;
  #pragma unroll
  for(int p=0;p<2;p++){
    int s = p ? s2 : s1;
    int k = p ? k2 : k1;
    int base = (b*FREQ_)*NSEG_;
    float v = ldb(iR, (base + 0*NSEG_ + s)*256 + h);
    float a8 = ldb(iR, (base + 8*NSEG_ + s)*256 + h);
    v += (k & 1) ? -a8 : a8;
    #pragma unroll
    for(int f=1;f<8;f++){
      int m = (f*k) & 15;
      float rr = ldb(iR, (base + f*NSEG_ + s)*256 + h);
      float ii = ldb(iI, (base + f*NSEG_ + s)*256 + h);
      v += 2.f*(rr*CT16[m] - ii*ST16[m]);
    }
    acc += 0.25f*v;
  }
  float z = 0.5f*acc + ldin<MODE>(inp, (b*SEQ_+t)*H_ + h);

  __shared__ float red[256];
  red[h] = z; __syncthreads();
  for(int off=128; off>0; off>>=1){ if(h<off) red[h] += red[h+off]; __syncthreads(); }
  float u = red[0] * (1.f/256.f);
  __syncthreads();
  float d = z - u;
  red[h] = d*d; __syncthreads();
  for(int off=128; off>0; off>>=1){ if(h<off) red[h] += red[h+off]; __syncthreads(); }
  float var = red[0] * (1.f/256.f);
  hs[(b*SEQ_+t)*H_ + h] = ldin<MODE>(lnw,h)*d*rsqrtf(var + 1e-12f) + ldin<MODE>(lnb,h);
}

// ---------------- Kernel 7: FFN layer 1 (256->1024, gelu) ----------------
template<int MODE>
__global__ __launch_bounds__(256) void k_ff1(const int* __restrict__ mf,
                                             const float* __restrict__ hs,
                                             const void* __restrict__ w1, const void* __restrict__ bb,
                                             float* __restrict__ hid, int row0){
  if(*mf != MODE) return;
  int r0 = blockIdx.x * 8; int t = threadIdx.x;
  __shared__ float xs[8][256];
  for(int r=0;r<8;r++) xs[r][t] = hs[(row0 + r0 + r)*256 + t];
  __syncthreads();
  float acc[4][8];
  #pragma unroll
  for(int c=0;c<4;c++){
    float bv = ldin<MODE>(bb, t + c*256);
    #pragma unroll
    for(int r=0;r<8;r++) acc[c][r] = bv;
  }
  for(int h=0; h<256; h++){
    float w0 = ldin<MODE>(w1, h*1024 + t);
    float w1v = ldin<MODE>(w1, h*1024 + t + 256);
    float w2v = ldin<MODE>(w1, h*1024 + t + 512);
    float w3v = ldin<MODE>(w1, h*1024 + t + 768);
    #pragma unroll
    for(int r=0;r<8;r++){
      float x = xs[r][h];
      acc[0][r] += x*w0; acc[1][r] += x*w1v; acc[2][r] += x*w2v; acc[3][r] += x*w3v;
    }
  }
  for(int c=0;c<4;c++)
    for(int r=0;r<8;r++)
      hid[(r0 + r)*1024 + t + c*256] = gelu_(acc[c][r]);
}

// ---------------- Kernel 8: FFN layer 2 + residual + LayerNorm -> out ----------------
template<int MODE>
__global__ __launch_bounds__(256) void k_ff2(const int* __restrict__ mf,
                                             const float* __restrict__ hid, const float* __restrict__ hs,
                                             const void* __restrict__ w2, const void* __restrict__ bb,
                                             const void* __restrict__ lnw, const void* __restrict__ lnb,
                                             void* __restrict__ out, int row0){
  if(*mf != MODE) return;
  int r0 = blockIdx.x * 8; int t = threadIdx.x;
  __shared__ float hd[8][1024];
  __shared__ float ot[8][256];
  for(int r=0;r<8;r++)
    for(int c=0;c<4;c++)
      hd[r][t + c*256] = hid[(r0 + r)*1024 + t + c*256];
  __syncthreads();
  float acc[8];
  float bv = ldin<MODE>(bb, t);
  #pragma unroll
  for(int r=0;r<8;r++) acc[r] = bv;
  for(int j=0; j<1024; j++){
    float wv = ldin<MODE>(w2, j*256 + t);
    #pragma unroll
    for(int r=0;r<8;r++) acc[r] += hd[r][j]*wv;
  }
  for(int r=0;r<8;r++) ot[r][t] = acc[r] + hs[(row0 + r0 + r)*256 + t];
  __syncthreads();
  int wid = t >> 6, lane = t & 63;
  for(int rr=0; rr<2; rr++){
    int r = wid*2 + rr;
    float v0 = ot[r][lane], v1 = ot[r][lane+64], v2 = ot[r][lane+128], v3 = ot[r][lane+192];
    float sm = v0+v1+v2+v3;
    for(int off=32; off>0; off>>=1) sm += __shfl_xor(sm, off);
    float u = sm * (1.f/256.f);
    float d0=v0-u, d1=v1-u, d2=v2-u, d3=v3-u;
    float sq = d0*d0 + d1*d1 + d2*d2 + d3*d3;
    for(int off=32; off>0; off>>=1) sq += __shfl_xor(sq, off);
    float inv = rsqrtf(sq*(1.f/256.f) + 1e-12f);
    int orow = (row0 + r0 + r)*256;
    stout<MODE>(out, orow + lane,       ldin<MODE>(lnw,lane)*d0*inv + ldin<MODE>(lnb,lane));
    stout<MODE>(out, orow + lane + 64,  ldin<MODE>(lnw,lane+64)*d1*inv + ldin<MODE>(lnb,lane+64));
    stout<MODE>(out, orow + lane + 128, ldin<MODE>(lnw,lane+128)*d2*inv + ldin<MODE>(lnb,lane+128));
    stout<MODE>(out, orow + lane + 192, ldin<MODE>(lnw,lane+192)*d3*inv + ldin<MODE>(lnb,lane+192));
  }
}

template<int MODE>
static void run_pipeline(void* const* d_in, void* d_out, void* d_ws, hipStream_t stream,
                         const int* mf, bf16* b0, bf16* b1, bf16* b2, bf16* b3,
                         float* wbuf, float* hs, float* hid){
  const void* inp    = d_in[0];
  const void* conv_w = d_in[1];
  const void* conv_b = d_in[2];
  const void* fm_w1  = d_in[3];
  const void* fm_b1  = d_in[4];
  const void* fm_w2  = d_in[5];
  const void* fm_b2  = d_in[6];
  const void* cm_w1  = d_in[7];
  const void* cm_b1  = d_in[8];
  const void* cm_w2  = d_in[9];
  const void* cm_b2  = d_in[10];
  const void* sm_w1  = d_in[11];
  const void* sm_b1  = d_in[12];
  const void* sm_w2  = d_in[13];
  const void* sm_b2  = d_in[14];
  const void* ln_w   = d_in[15];
  const void* ln_b   = d_in[16];
  const void* ff_w1  = d_in[17];
  const void* ff_b1  = d_in[18];
  const void* ff_w2  = d_in[19];
  const void* ff_b2  = d_in[20];
  const void* ffln_w = d_in[21];
  const void* ffln_b = d_in[22];

  k_stft<MODE><<<B_*NSEG_, 256, 0, stream>>>(mf, inp, b0, b1);
  k_w<MODE><<<B_*NSEG_, 256, 0, stream>>>(mf, b0, b1, conv_w, conv_b, wbuf);
  k_fm<MODE><<<B_*NSEG_, 256, 0, stream>>>(mf, b0, b1, wbuf, fm_w1, fm_b1, fm_w2, fm_b2, b2, b3);
  k_cm<MODE><<<NSEG_*288, 256, 0, stream>>>(mf, b2, b3, cm_w1, cm_b1, cm_w2, cm_b2, b0, b1);
  k_sm<MODE><<<B_*FREQ_, 256, 0, stream>>>(mf, b0, b1, sm_w1, sm_b1, sm_w2, sm_b2, b2, b3);
  k_ist<MODE><<<B_*SEQ_, 256, 0, stream>>>(mf, b2, b3, inp, ln_w, ln_b, hs);
  for(int c=0; c<4; c++){
    int row0 = c*12800;
    k_ff1<MODE><<<1600, 256, 0, stream>>>(mf, hs, ff_w1, ff_b1, hid, row0);
    k_ff2<MODE><<<1600, 256, 0, stream>>>(mf, hid, hs, ff_w2, ff_b2, ffln_w, ffln_b, d_out, row0);
  }
}

extern "C" void kernel_launch(void* const* d_in, const int* in_sizes, int n_in,
                              void* d_out, int out_size, void* d_ws, size_t ws_size,
                              hipStream_t stream){
  const size_t NS = (size_t)B_ * NSEG_ * FREQ_ * H_;   // 15,335,424 elements
  // workspace: A-pair (b0,b1) | B-pair (b2,b3) as bf16, wbuf fp32, flag.
  // hs (fp32) aliases region A (dead after k_sm); hid (fp32 chunk) aliases region B.
  bf16* b0 = (bf16*)d_ws;
  bf16* b1 = b0 + NS;
  bf16* b2 = b1 + NS;
  bf16* b3 = b2 + NS;
  float* wbuf = (float*)(b3 + NS);
  int* flag = (int*)(wbuf + B_*NSEG_);
  float* hs  = (float*)b0;
  float* hid = (float*)b2;

  k_detect<<<1, 256, 0, stream>>>((const unsigned short*)d_in[0], flag);
  run_pipeline<0>(d_in, d_out, d_ws, stream, flag, b0, b1, b2, b3, wbuf, hs, hid);
  run_pipeline<1>(d_in, d_out, d_ws, stream, flag, b0, b1, b2, b3, wbuf, hs, hid);
}

// Round 4
// 4127.936 us; speedup vs baseline: 2.4865x; 2.4865x over previous
//
#include <hip/hip_runtime.h>
#include <hip/hip_bf16.h>
#include <math.h>

typedef __hip_bfloat16 bf16;

#define B_    256
#define SEQ_  200
#define H_    256
#define FREQ_ 9
#define NSEG_ 26

// MODE 0: external tensors are bf16. MODE 1: external tensors are fp32.
template<int MODE> __device__ __forceinline__ float ldin(const void* p, int i){
  if constexpr(MODE==0) return __bfloat162float(((const bf16*)p)[i]);
  else                  return ((const float*)p)[i];
}
template<int MODE> __device__ __forceinline__ void stout(void* p, int i, float v){
  if constexpr(MODE==0) ((bf16*)p)[i] = __float2bfloat16(v);
  else                  ((float*)p)[i] = v;
}
__device__ __forceinline__ float ldb(const bf16* p, int i){ return __bfloat162float(p[i]); }
__device__ __forceinline__ void stb(bf16* p, int i, float v){ p[i] = __float2bfloat16(v); }
__device__ __forceinline__ float gelu_(float x){ return 0.5f*x*(1.0f+erff(x*0.7071067811865475f)); }

__device__ __forceinline__ unsigned short bf2u(bf16 v){ union{bf16 b; unsigned short u;} c; c.b=v; return c.u; }
__device__ __forceinline__ float u2f(unsigned short u){ union{bf16 b; unsigned short u;} c; c.u=u; return __bfloat162float(c.b); }

// cos(m*pi/8), sin(m*pi/8), m=0..15
__device__ __constant__ float CT16[16] = {
  1.0f, 0.9238795325f, 0.7071067812f, 0.3826834324f, 0.0f, -0.3826834324f, -0.7071067812f, -0.9238795325f,
 -1.0f,-0.9238795325f,-0.7071067812f,-0.3826834324f, 0.0f,  0.3826834324f, 0.7071067812f,  0.9238795325f};
__device__ __constant__ float ST16[16] = {
  0.0f, 0.3826834324f, 0.7071067812f, 0.9238795325f, 1.0f,  0.9238795325f, 0.7071067812f,  0.3826834324f,
  0.0f,-0.3826834324f,-0.7071067812f,-0.9238795325f,-1.0f, -0.9238795325f,-0.7071067812f, -0.3826834324f};

// ---------------- dtype detector ----------------
__global__ __launch_bounds__(256) void k_detect(const unsigned short* __restrict__ u,
                                                int* __restrict__ flag){
  int t = threadIdx.x;
  int cnt = 0;
  for(int i=t; i<2048; i+=256){
    unsigned short v = u[2*i];
    int e = (v >> 7) & 0xFF;
    if(e == 0xFF || e < 64) cnt++;
  }
  __shared__ int red[256];
  red[t] = cnt; __syncthreads();
  for(int off=128; off>0; off>>=1){ if(t<off) red[t]+=red[t+off]; __syncthreads(); }
  if(t==0) *flag = (red[0] > 64) ? 1 : 0;
}

// ---------------- Kernel 1: STFT ----------------
template<int MODE>
__global__ __launch_bounds__(256) void k_stft(const int* __restrict__ mf,
                                              const void* __restrict__ inp,
                                              bf16* __restrict__ sR, bf16* __restrict__ sI){
  if(*mf != MODE) return;
  int blk = blockIdx.x; int b = blk / NSEG_; int s = blk % NSEG_; int h = threadIdx.x;
  float xv[16];
  int t0 = s*8 - 8;
  #pragma unroll
  for(int k=0;k<16;k++){
    int t = t0 + k;
    xv[k] = (t>=0 && t<SEQ_) ? ldin<MODE>(inp, (b*SEQ_+t)*H_ + h) : 0.0f;
  }
  #pragma unroll
  for(int f=0;f<FREQ_;f++){
    float ar=0.f, ai=0.f;
    #pragma unroll
    for(int k=0;k<16;k++){
      int m = (f*k) & 15;
      ar += xv[k]*CT16[m];
      ai -= xv[k]*ST16[m];
    }
    int idx = ((b*NSEG_+s)*FREQ_+f)*H_ + h;
    stb(sR, idx, 0.25f*ar);
    stb(sI, idx, 0.25f*ai);
  }
}

// ---------------- Kernel 2: gating weight w[b,s] ----------------
template<int MODE>
__global__ __launch_bounds__(256) void k_w(const int* __restrict__ mf,
                                           const bf16* __restrict__ sR, const bf16* __restrict__ sI,
                                           const void* __restrict__ cw, const void* __restrict__ cb,
                                           float* __restrict__ wout){
  if(*mf != MODE) return;
  int blk = blockIdx.x; int b = blk / NSEG_; int s = blk % NSEG_; int h = threadIdx.x;
  float acc = 0.f;
  #pragma unroll
  for(int f=0;f<FREQ_;f++){
    int idx = ((b*NSEG_+s)*FREQ_+f)*H_ + h;
    float r = ldb(sR, idx), i = ldb(sI, idx);
    acc += sqrtf(r*r + i*i) * ldin<MODE>(cw, (s*H_+h)*FREQ_ + f);
  }
  __shared__ float red[256];
  red[h] = acc; __syncthreads();
  for(int off=128; off>0; off>>=1){ if(h<off) red[h] += red[h+off]; __syncthreads(); }
  if(h==0) wout[b*NSEG_+s] = red[0] + ldin<MODE>(cb, s) + __expf((float)(s - (NSEG_-1)));
}

// ---------------- Kernel 3: frequency mixer (9->18->9) ----------------
template<int MODE>
__global__ __launch_bounds__(256) void k_fm(const int* __restrict__ mf,
                                            const bf16* __restrict__ sR, const bf16* __restrict__ sI,
                                            const float* __restrict__ wv_,
                                            const void* __restrict__ w1, const void* __restrict__ bb1,
                                            const void* __restrict__ w2, const void* __restrict__ bb2,
                                            bf16* __restrict__ oR, bf16* __restrict__ oI){
  if(*mf != MODE) return;
  int blk = blockIdx.x; int b = blk / NSEG_; int s = blk % NSEG_; int h = threadIdx.x;
  __shared__ float2 lw1[162], lw2[162], lb1[18], lb2[9];
  for(int i=threadIdx.x; i<162; i+=256){
    lw1[i] = make_float2(ldin<MODE>(w1, s*162+i), ldin<MODE>(w1, 4212 + s*162+i));
    lw2[i] = make_float2(ldin<MODE>(w2, s*162+i), ldin<MODE>(w2, 4212 + s*162+i));
  }
  if(threadIdx.x < 18) lb1[threadIdx.x] = make_float2(ldin<MODE>(bb1, s*18+threadIdx.x), ldin<MODE>(bb1, 468 + s*18+threadIdx.x));
  if(threadIdx.x < 9)  lb2[threadIdx.x] = make_float2(ldin<MODE>(bb2, s*9+threadIdx.x),  ldin<MODE>(bb2, 234 + s*9+threadIdx.x));
  __syncthreads();

  float wv = wv_[b*NSEG_+s];
  float xr[9], xi[9];
  #pragma unroll
  for(int f=0;f<9;f++){
    int idx = ((b*NSEG_+s)*FREQ_+f)*H_ + h;
    xr[f] = ldb(sR, idx)*wv; xi[f] = ldb(sI, idx)*wv;
  }
  float gr[18], gi[18];
  #pragma unroll
  for(int j=0;j<18;j++){
    float hr = lb1[j].x, hi = lb1[j].y;
    #pragma unroll
    for(int f=0;f<9;f++){
      float2 ww = lw1[f*18+j];
      hr += xr[f]*ww.x - xi[f]*ww.y;
      hi += xi[f]*ww.x + xr[f]*ww.y;
    }
    gr[j] = gelu_(hr); gi[j] = gelu_(hi);
  }
  #pragma unroll
  for(int f=0;f<9;f++){
    float orr = lb2[f].x, oii = lb2[f].y;
    #pragma unroll
    for(int j=0;j<18;j++){
      float2 ww = lw2[j*9+f];
      orr += gr[j]*ww.x - gi[j]*ww.y;
      oii += gi[j]*ww.x + gi[j]*ww.y;   // reference bug: o2i uses o1i with BOTH w2[0] and w2[1]
    }
    int o = ((s*B_+b)*FREQ_+f)*H_ + h;
    stb(oR, o, orr); stb(oI, o, oii);
  }
}

// ---------------- Kernel 4: channel mixer (256->512->256) ----------------
template<int MODE>
__global__ __launch_bounds__(256) void k_cm(const int* __restrict__ mf,
                                            const bf16* __restrict__ iR, const bf16* __restrict__ iI,
                                            const void* __restrict__ w1, const void* __restrict__ bb1,
                                            const void* __restrict__ w2, const void* __restrict__ bb2,
                                            bf16* __restrict__ oR, bf16* __restrict__ oI){
  if(*mf != MODE) return;
  int s = blockIdx.x / 288; int g = blockIdx.x % 288; int t = threadIdx.x;
  __shared__ float2 xx[8][256];
  __shared__ float2 hh[8][512];
  int row0 = g*8;
  for(int r=0;r<8;r++){
    int idx = (s*2304 + row0 + r)*256 + t;
    xx[r][t] = make_float2(ldb(iR, idx), ldb(iI, idx));
  }
  __syncthreads();
  float a0r[8], a0i[8], a1r[8], a1i[8];
  {
    float b0r = ldin<MODE>(bb1, s*512 + t),       b0i = ldin<MODE>(bb1, 13312 + s*512 + t);
    float b1r = ldin<MODE>(bb1, s*512 + t + 256), b1i = ldin<MODE>(bb1, 13312 + s*512 + t + 256);
    #pragma unroll
    for(int r=0;r<8;r++){ a0r[r]=b0r; a0i[r]=b0i; a1r[r]=b1r; a1i[r]=b1i; }
  }
  for(int h=0; h<256; h++){
    int base = (s*256 + h)*512;
    float w10a = ldin<MODE>(w1, base + t);
    float w10b = ldin<MODE>(w1, base + t + 256);
    float w11a = ldin<MODE>(w1, 3407872 + base + t);
    float w11b = ldin<MODE>(w1, 3407872 + base + t + 256);
    #pragma unroll
    for(int r=0;r<8;r++){
      float2 x = xx[r][h];
      a0r[r] += x.x*w10a - x.y*w11a;
      a0i[r] += x.y*w10a + x.x*w11a;
      a1r[r] += x.x*w10b - x.y*w11b;
      a1i[r] += x.y*w10b + x.x*w11b;
    }
  }
  #pragma unroll
  for(int r=0;r<8;r++){
    hh[r][t]     = make_float2(gelu_(a0r[r]), gelu_(a0i[r]));
    hh[r][t+256] = make_float2(gelu_(a1r[r]), gelu_(a1i[r]));
  }
  __syncthreads();
  float o_r[8], o_i[8];
  {
    float br = ldin<MODE>(bb2, s*256 + t), bi = ldin<MODE>(bb2, 6656 + s*256 + t);
    #pragma unroll
    for(int r=0;r<8;r++){ o_r[r]=br; o_i[r]=bi; }
  }
  for(int j=0; j<512; j++){
    int base = (s*512 + j)*256;
    float w20 = ldin<MODE>(w2, base + t);
    float w21 = ldin<MODE>(w2, 3407872 + base + t);
    float w2s = w20 + w21;
    #pragma unroll
    for(int r=0;r<8;r++){
      float2 hv = hh[r][j];
      o_r[r] += hv.x*w20 - hv.y*w21;
      o_i[r] += hv.y*w2s;             // reference bug replicated
    }
  }
  for(int r=0;r<8;r++){
    int o = ((row0 + r)*NSEG_ + s)*256 + t;
    stb(oR, o, o_r[r]); stb(oI, o, o_i[r]);
  }
}

// ---------------- Kernel 5: segment mixer (26->52->26) ----------------
// RESTRUCTURED (R4): x in LDS (packed bf16 pairs, per-thread column -> conflict-free),
// only the 52 output accumulators live in VGPRs; j-loop NOT unrolled.
// Old version: 104 live floats + full unroll -> VGPR=256 + 9.5 GB scratch spill traffic.
template<int MODE>
__global__ __launch_bounds__(256) void k_sm(const int* __restrict__ mf,
                                            const bf16* __restrict__ iR, const bf16* __restrict__ iI,
                                            const void* __restrict__ w1, const void* __restrict__ bb1,
                                            const void* __restrict__ w2, const void* __restrict__ bb2,
                                            bf16* __restrict__ oR, bf16* __restrict__ oI){
  if(*mf != MODE) return;
  int bq = blockIdx.x / FREQ_; int f = blockIdx.x % FREQ_; int h = threadIdx.x;
  __shared__ float2 lw1[1352];           // [s*52+j] = (w10, w11)   10.8 KB
  __shared__ float2 lw2[1352];           // [j*26+so] = (w20, w21)  10.8 KB
  __shared__ float2 lb1[52], lb2[26];
  __shared__ unsigned xls[26][256];      // packed bf16 (r,i) per (s,h)  26.6 KB
  for(int i=threadIdx.x; i<1352; i+=256){
    lw1[i] = make_float2(ldin<MODE>(w1, f*1352+i), ldin<MODE>(w1, 12168 + f*1352+i));
    lw2[i] = make_float2(ldin<MODE>(w2, f*1352+i), ldin<MODE>(w2, 12168 + f*1352+i));
  }
  if(threadIdx.x < 52) lb1[threadIdx.x] = make_float2(ldin<MODE>(bb1, f*52+threadIdx.x), ldin<MODE>(bb1, 468 + f*52+threadIdx.x));
  if(threadIdx.x < 26) lb2[threadIdx.x] = make_float2(ldin<MODE>(bb2, f*26+threadIdx.x), ldin<MODE>(bb2, 234 + f*26+threadIdx.x));

  int rbase = (bq*FREQ_+f)*NSEG_;
  // stage x into LDS (lossless: values already bf16 in global)
  #pragma unroll
  for(int s=0;s<26;s++){
    int idx = (rbase + s)*256 + h;
    xls[s][h] = (unsigned)bf2u(iR[idx]) | ((unsigned)bf2u(iI[idx]) << 16);
  }
  __syncthreads();

  float o_r[26], o_i[26];
  #pragma unroll
  for(int so=0;so<26;so++){ o_r[so] = lb2[so].x; o_i[so] = lb2[so].y; }

  #pragma unroll 1
  for(int j=0;j<52;j++){
    float hr = lb1[j].x, hi = lb1[j].y;
    #pragma unroll
    for(int s=0;s<26;s++){
      unsigned v = xls[s][h];
      float xr_ = u2f((unsigned short)(v & 0xFFFF));
      float xi_ = u2f((unsigned short)(v >> 16));
      float2 ww = lw1[s*52+j];
      hr += xr_*ww.x - xi_*ww.y;
      hi += xi_*ww.x + xr_*ww.y;
    }
    hr = gelu_(hr); hi = gelu_(hi);
    #pragma unroll
    for(int so=0;so<26;so++){
      float2 ww = lw2[j*26+so];
      o_r[so] += hr*ww.x - hi*ww.y;
      o_i[so] += hi*(ww.x + ww.y);   // reference bug replicated
    }
  }
  #pragma unroll
  for(int so=0;so<26;so++){
    int o = (rbase + so)*256 + h;
    stb(oR, o, o_r[so]); stb(oI, o, o_i[so]);
  }
}

// ---------------- Kernel 6: iSTFT + residual + LayerNorm ----------------
template<int MODE>
__global__ __launch_bounds__(256) void k_ist(const int* __restrict__ mf,
                                             const bf16* __restrict__ iR, const bf16* __restrict__ iI,
                                             const void* __restrict__ inp,
                                             const void* __restrict__ lnw, const void* __restrict__ lnb,
                                             float* __restrict__ hs){
  if(*mf != MODE) return;
  int blk = blockIdx.x; int b = blk / SEQ_; int t = blk % SEQ_; int h = threadIdx.x;
  int l = t + 8;
  int s2 = l >> 3, k2 = l & 7;
  int s1 = s2 - 1, k1 = k2 + 8;
  float acc = 0.f;
  #pragma unroll
  for(int p=0;p<2;p++){
    int s = p ? s2 : s1;
    int k = p ? k2 : k1;
    int base = (b*FREQ_)*NSEG_;
    float v = ldb(iR, (base + 0*NSEG_ + s)*256 + h);
    float a8 = ldb(iR, (base + 8*NSEG_ + s)*256 + h);
    v += (k & 1) ? -a8 : a8;
    #pragma unroll
    for(int f=1;f<8;f++){
      int m = (f*k) & 15;
      float rr = ldb(iR, (base + f*NSEG_ + s)*256 + h);
      float ii = ldb(iI, (base + f*NSEG_ + s)*256 + h);
      v += 2.f*(rr*CT16[m] - ii*ST16[m]);
    }
    acc += 0.25f*v;
  }
  float z = 0.5f*acc + ldin<MODE>(inp, (b*SEQ_+t)*H_ + h);

  __shared__ float red[256];
  red[h] = z; __syncthreads();
  for(int off=128; off>0; off>>=1){ if(h<off) red[h] += red[h+off]; __syncthreads(); }
  float u = red[0] * (1.f/256.f);
  __syncthreads();
  float d = z - u;
  red[h] = d*d; __syncthreads();
  for(int off=128; off>0; off>>=1){ if(h<off) red[h] += red[h+off]; __syncthreads(); }
  float var = red[0] * (1.f/256.f);
  hs[(b*SEQ_+t)*H_ + h] = ldin<MODE>(lnw,h)*d*rsqrtf(var + 1e-12f) + ldin<MODE>(lnb,h);
}

// ---------------- Kernel 7: FFN layer 1 (256->1024, gelu) ----------------
template<int MODE>
__global__ __launch_bounds__(256) void k_ff1(const int* __restrict__ mf,
                                             const float* __restrict__ hs,
                                             const void* __restrict__ w1, const void* __restrict__ bb,
                                             float* __restrict__ hid, int row0){
  if(*mf != MODE) return;
  int r0 = blockIdx.x * 8; int t = threadIdx.x;
  __shared__ float xs[8][256];
  for(int r=0;r<8;r++) xs[r][t] = hs[(row0 + r0 + r)*256 + t];
  __syncthreads();
  float acc[4][8];
  #pragma unroll
  for(int c=0;c<4;c++){
    float bv = ldin<MODE>(bb, t + c*256);
    #pragma unroll
    for(int r=0;r<8;r++) acc[c][r] = bv;
  }
  for(int h=0; h<256; h++){
    float w0 = ldin<MODE>(w1, h*1024 + t);
    float w1v = ldin<MODE>(w1, h*1024 + t + 256);
    float w2v = ldin<MODE>(w1, h*1024 + t + 512);
    float w3v = ldin<MODE>(w1, h*1024 + t + 768);
    #pragma unroll
    for(int r=0;r<8;r++){
      float x = xs[r][h];
      acc[0][r] += x*w0; acc[1][r] += x*w1v; acc[2][r] += x*w2v; acc[3][r] += x*w3v;
    }
  }
  for(int c=0;c<4;c++)
    for(int r=0;r<8;r++)
      hid[(r0 + r)*1024 + t + c*256] = gelu_(acc[c][r]);
}

// ---------------- Kernel 8: FFN layer 2 + residual + LayerNorm -> out ----------------
template<int MODE>
__global__ __launch_bounds__(256) void k_ff2(const int* __restrict__ mf,
                                             const float* __restrict__ hid, const float* __restrict__ hs,
                                             const void* __restrict__ w2, const void* __restrict__ bb,
                                             const void* __restrict__ lnw, const void* __restrict__ lnb,
                                             void* __restrict__ out, int row0){
  if(*mf != MODE) return;
  int r0 = blockIdx.x * 8; int t = threadIdx.x;
  __shared__ float hd[8][1024];
  __shared__ float ot[8][256];
  for(int r=0;r<8;r++)
    for(int c=0;c<4;c++)
      hd[r][t + c*256] = hid[(r0 + r)*1024 + t + c*256];
  __syncthreads();
  float acc[8];
  float bv = ldin<MODE>(bb, t);
  #pragma unroll
  for(int r=0;r<8;r++) acc[r] = bv;
  for(int j=0; j<1024; j++){
    float wv = ldin<MODE>(w2, j*256 + t);
    #pragma unroll
    for(int r=0;r<8;r++) acc[r] += hd[r][j]*wv;
  }
  for(int r=0;r<8;r++) ot[r][t] = acc[r] + hs[(row0 + r0 + r)*256 + t];
  __syncthreads();
  int wid = t >> 6, lane = t & 63;
  for(int rr=0; rr<2; rr++){
    int r = wid*2 + rr;
    float v0 = ot[r][lane], v1 = ot[r][lane+64], v2 = ot[r][lane+128], v3 = ot[r][lane+192];
    float sm = v0+v1+v2+v3;
    for(int off=32; off>0; off>>=1) sm += __shfl_xor(sm, off);
    float u = sm * (1.f/256.f);
    float d0=v0-u, d1=v1-u, d2=v2-u, d3=v3-u;
    float sq = d0*d0 + d1*d1 + d2*d2 + d3*d3;
    for(int off=32; off>0; off>>=1) sq += __shfl_xor(sq, off);
    float inv = rsqrtf(sq*(1.f/256.f) + 1e-12f);
    int orow = (row0 + r0 + r)*256;
    stout<MODE>(out, orow + lane,       ldin<MODE>(lnw,lane)*d0*inv + ldin<MODE>(lnb,lane));
    stout<MODE>(out, orow + lane + 64,  ldin<MODE>(lnw,lane+64)*d1*inv + ldin<MODE>(lnb,lane+64));
    stout<MODE>(out, orow + lane + 128, ldin<MODE>(lnw,lane+128)*d2*inv + ldin<MODE>(lnb,lane+128));
    stout<MODE>(out, orow + lane + 192, ldin<MODE>(lnw,lane+192)*d3*inv + ldin<MODE>(lnb,lane+192));
  }
}

template<int MODE>
static void run_pipeline(void* const* d_in, void* d_out, void* d_ws, hipStream_t stream,
                         const int* mf, bf16* b0, bf16* b1, bf16* b2, bf16* b3,
                         float* wbuf, float* hs, float* hid){
  const void* inp    = d_in[0];
  const void* conv_w = d_in[1];
  const void* conv_b = d_in[2];
  const void* fm_w1  = d_in[3];
  const void* fm_b1  = d_in[4];
  const void* fm_w2  = d_in[5];
  const void* fm_b2  = d_in[6];
  const void* cm_w1  = d_in[7];
  const void* cm_b1  = d_in[8];
  const void* cm_w2  = d_in[9];
  const void* cm_b2  = d_in[10];
  const void* sm_w1  = d_in[11];
  const void* sm_b1  = d_in[12];
  const void* sm_w2  = d_in[13];
  const void* sm_b2  = d_in[14];
  const void* ln_w   = d_in[15];
  const void* ln_b   = d_in[16];
  const void* ff_w1  = d_in[17];
  const void* ff_b1  = d_in[18];
  const void* ff_w2  = d_in[19];
  const void* ff_b2  = d_in[20];
  const void* ffln_w = d_in[21];
  const void* ffln_b = d_in[22];

  k_stft<MODE><<<B_*NSEG_, 256, 0, stream>>>(mf, inp, b0, b1);
  k_w<MODE><<<B_*NSEG_, 256, 0, stream>>>(mf, b0, b1, conv_w, conv_b, wbuf);
  k_fm<MODE><<<B_*NSEG_, 256, 0, stream>>>(mf, b0, b1, wbuf, fm_w1, fm_b1, fm_w2, fm_b2, b2, b3);
  k_cm<MODE><<<NSEG_*288, 256, 0, stream>>>(mf, b2, b3, cm_w1, cm_b1, cm_w2, cm_b2, b0, b1);
  k_sm<MODE><<<B_*FREQ_, 256, 0, stream>>>(mf, b0, b1, sm_w1, sm_b1, sm_w2, sm_b2, b2, b3);
  k_ist<MODE><<<B_*SEQ_, 256, 0, stream>>>(mf, b2, b3, inp, ln_w, ln_b, hs);
  for(int c=0; c<4; c++){
    int row0 = c*12800;
    k_ff1<MODE><<<1600, 256, 0, stream>>>(mf, hs, ff_w1, ff_b1, hid, row0);
    k_ff2<MODE><<<1600, 256, 0, stream>>>(mf, hid, hs, ff_w2, ff_b2, ffln_w, ffln_b, d_out, row0);
  }
}

extern "C" void kernel_launch(void* const* d_in, const int* in_sizes, int n_in,
                              void* d_out, int out_size, void* d_ws, size_t ws_size,
                              hipStream_t stream){
  const size_t NS = (size_t)B_ * NSEG_ * FREQ_ * H_;   // 15,335,424 elements
  bf16* b0 = (bf16*)d_ws;
  bf16* b1 = b0 + NS;
  bf16* b2 = b1 + NS;
  bf16* b3 = b2 + NS;
  float* wbuf = (float*)(b3 + NS);
  int* flag = (int*)(wbuf + B_*NSEG_);
  float* hs  = (float*)b0;
  float* hid = (float*)b2;

  k_detect<<<1, 256, 0, stream>>>((const unsigned short*)d_in[0], flag);
  run_pipeline<0>(d_in, d_out, d_ws, stream, flag, b0, b1, b2, b3, wbuf, hs, hid);
  run_pipeline<1>(d_in, d_out, d_ws, stream, flag, b0, b1, b2, b3, wbuf, hs, hid);
}

// Round 5
// 1160.828 us; speedup vs baseline: 8.8422x; 3.5560x over previous
//
#include <hip/hip_runtime.h>
#include <hip/hip_bf16.h>
#include <math.h>

typedef __hip_bfloat16 bf16;
typedef short bf16x8 __attribute__((ext_vector_type(8)));
typedef float f32x4 __attribute__((ext_vector_type(4)));

#define B_    256
#define SEQ_  200
#define H_    256
#define FREQ_ 9
#define NSEG_ 26
#define LDK   72   // 64 + 8 pad shorts: 2-way LDS bank aliasing only (free)

__device__ __forceinline__ float ldb(const bf16* p, size_t i){ return __bfloat162float(p[i]); }
__device__ __forceinline__ void stb(bf16* p, size_t i, float v){ p[i] = __float2bfloat16(v); }
__device__ __forceinline__ short f2b(float v){ union{bf16 b; short s;} c; c.b = __float2bfloat16(v); return c.s; }
__device__ __forceinline__ float gelu_(float x){ return 0.5f*x*(1.0f+erff(x*0.7071067811865475f)); }

__device__ __constant__ float CT16[16] = {
  1.0f, 0.9238795325f, 0.7071067812f, 0.3826834324f, 0.0f, -0.3826834324f, -0.7071067812f, -0.9238795325f,
 -1.0f,-0.9238795325f,-0.7071067812f,-0.3826834324f, 0.0f,  0.3826834324f, 0.7071067812f,  0.9238795325f};
__device__ __constant__ float ST16[16] = {
  0.0f, 0.3826834324f, 0.7071067812f, 0.9238795325f, 1.0f,  0.9238795325f, 0.7071067812f,  0.3826834324f,
  0.0f,-0.3826834324f,-0.7071067812f,-0.9238795325f,-1.0f, -0.9238795325f,-0.7071067812f, -0.3826834324f};

// =================== shared MFMA GEMM machinery ===================
// stage ROWS x 64 bf16 tile from global [row][k] (k-contiguous) into LDS [ROWS][LDK]
template<int ROWS>
__device__ __forceinline__ void stage_tile(short* lds, const short* src, int rstride, int tid){
  #pragma unroll
  for(int p=0; p<ROWS/32; p++){
    int row = p*32 + (tid>>3);
    int ko  = (tid&7)*8;
    *(int4*)&lds[row*LDK + ko] = *(const int4*)&src[(size_t)row*rstride + ko];
  }
}

// one BK=64 step: wave computes 64x64 via 4x4 grid of 16x16x32 MFMA
__device__ __forceinline__ void mma_bk64(const short* lA, const short* lB, int wm, int wn,
                                         int lane, f32x4 acc[4][4]){
  int m_l = lane & 15, quad = lane >> 4;
  #pragma unroll
  for(int ks=0; ks<64; ks+=32){
    bf16x8 a[4], b[4];
    #pragma unroll
    for(int i=0;i<4;i++) a[i] = *(const bf16x8*)&lA[(wm + i*16 + m_l)*LDK + ks + quad*8];
    #pragma unroll
    for(int j=0;j<4;j++) b[j] = *(const bf16x8*)&lB[(wn + j*16 + m_l)*LDK + ks + quad*8];
    #pragma unroll
    for(int i=0;i<4;i++)
      #pragma unroll
      for(int j=0;j<4;j++)
        acc[i][j] = __builtin_amdgcn_mfma_f32_16x16x32_bf16(a[i], b[j], acc[i][j], 0,0,0);
  }
}

// =================== prep: weight repack (fp32 -> transposed bf16) ===================
// B1t[s][n=1024][k=512]: n<512: [W10 ; -W11]; n>=512: [W11 ; W10]  (k-major rows)
__global__ __launch_bounds__(256) void k_prep_b1(const float* __restrict__ w1, short* __restrict__ B1t){
  int g = blockIdx.x;
  int jt = g & 7, ht = (g>>3)&3, p = (g>>5)&1, s = g>>6;   // 26*64 = 1664 blocks
  __shared__ float tile[64][65];
  int t = threadIdx.x;
  const float* src = w1 + (size_t)p*3407872 + (size_t)s*131072;
  #pragma unroll
  for(int q=0;q<16;q++){
    int r = q*4 + (t>>6), c = t & 63;
    tile[r][c] = src[(size_t)(ht*64 + r)*512 + jt*64 + c];   // W1p[h][j]
  }
  __syncthreads();
  int n_l = t >> 2, kc = (t & 3)*16;
  short tA[16] __attribute__((aligned(16)));
  short tB[16] __attribute__((aligned(16)));
  #pragma unroll
  for(int i=0;i<16;i++){
    float v = tile[kc+i][n_l];
    tA[i] = (p==0) ? f2b(v) : f2b(-v);
    tB[i] = f2b(v);
  }
  int j = jt*64 + n_l, h = ht*64 + kc;
  size_t d1, d2;
  if(p==0){ d1 = ((size_t)(s*1024 + j))*512 + h;            // W10 -> [j][h]
            d2 = ((size_t)(s*1024 + 512 + j))*512 + 256 + h; }  // W10 -> [512+j][256+h]
  else    { d1 = ((size_t)(s*1024 + j))*512 + 256 + h;      // -W11 -> [j][256+h]
            d2 = ((size_t)(s*1024 + 512 + j))*512 + h; }    // +W11 -> [512+j][h]
  *(int4*)&B1t[d1] = *(int4*)&tA[0]; *(int4*)&B1t[d1+8] = *(int4*)&tA[8];
  *(int4*)&B1t[d2] = *(int4*)&tB[0]; *(int4*)&B1t[d2+8] = *(int4*)&tB[8];
}

// B2r[s][n=256][k=1024] = [W20 ; -W21]^T ; B2i[s][n=256][k=512] = (W20+W21)^T
__global__ __launch_bounds__(256) void k_prep_b2(const float* __restrict__ w2,
                                                 short* __restrict__ B2r, short* __restrict__ B2i){
  int g = blockIdx.x;
  int ht = g & 3, jt = (g>>2)&7, s = g>>5;                  // 26*32 = 832 blocks
  __shared__ float t0[64][65], t1[64][65];
  int t = threadIdx.x;
  const float* s0 = w2 + (size_t)s*131072;
  const float* s1 = w2 + 3407872 + (size_t)s*131072;
  #pragma unroll
  for(int q=0;q<16;q++){
    int r = q*4 + (t>>6), c = t & 63;
    t0[r][c] = s0[(size_t)(jt*64 + r)*256 + ht*64 + c];     // W20[j][h]
    t1[r][c] = s1[(size_t)(jt*64 + r)*256 + ht*64 + c];
  }
  __syncthreads();
  int n_l = t >> 2, jc = (t & 3)*16;
  short ta[16] __attribute__((aligned(16)));
  short tb[16] __attribute__((aligned(16)));
  short tc[16] __attribute__((aligned(16)));
  #pragma unroll
  for(int i=0;i<16;i++){
    float v0 = t0[jc+i][n_l], v1 = t1[jc+i][n_l];
    ta[i] = f2b(v0); tb[i] = f2b(-v1); tc[i] = f2b(v0+v1);
  }
  int n = ht*64 + n_l, j = jt*64 + jc;
  size_t dr = ((size_t)(s*256 + n))*1024 + j;
  size_t di = ((size_t)(s*256 + n))*512 + j;
  *(int4*)&B2r[dr]     = *(int4*)&ta[0]; *(int4*)&B2r[dr+8]     = *(int4*)&ta[8];
  *(int4*)&B2r[dr+512] = *(int4*)&tb[0]; *(int4*)&B2r[dr+520]   = *(int4*)&tb[8];
  *(int4*)&B2i[di]     = *(int4*)&tc[0]; *(int4*)&B2i[di+8]     = *(int4*)&tc[8];
}

// generic transpose fp32 [R][C] -> bf16 [C][R]
__global__ __launch_bounds__(256) void k_transp(const float* __restrict__ src, short* __restrict__ dst,
                                                int R, int C){
  int ct = blockIdx.x % (C/64);
  int rt = blockIdx.x / (C/64);
  __shared__ float tile[64][65];
  int t = threadIdx.x;
  #pragma unroll
  for(int p=0;p<16;p++){
    int r = p*4 + (t>>6), c = t & 63;
    tile[r][c] = src[(size_t)(rt*64 + r)*C + ct*64 + c];
  }
  __syncthreads();
  int row_out = t >> 2, rc = (t & 3)*16;
  short tmp[16] __attribute__((aligned(16)));
  #pragma unroll
  for(int i=0;i<16;i++) tmp[i] = f2b(tile[rc+i][row_out]);
  size_t base = (size_t)(ct*64 + row_out)*R + rt*64 + rc;
  *(int4*)&dst[base] = *(int4*)&tmp[0]; *(int4*)&dst[base+8] = *(int4*)&tmp[8];
}

// =================== Kernel 1: STFT ===================
__global__ __launch_bounds__(256) void k_stft(const float* __restrict__ inp,
                                              bf16* __restrict__ sR, bf16* __restrict__ sI){
  int blk = blockIdx.x; int b = blk / NSEG_; int s = blk % NSEG_; int h = threadIdx.x;
  float xv[16];
  int t0 = s*8 - 8;
  #pragma unroll
  for(int k=0;k<16;k++){
    int t = t0 + k;
    xv[k] = (t>=0 && t<SEQ_) ? inp[(size_t)(b*SEQ_+t)*H_ + h] : 0.0f;
  }
  #pragma unroll
  for(int f=0;f<FREQ_;f++){
    float ar=0.f, ai=0.f;
    #pragma unroll
    for(int k=0;k<16;k++){
      int m = (f*k) & 15;
      ar += xv[k]*CT16[m];
      ai -= xv[k]*ST16[m];
    }
    size_t idx = ((size_t)(b*NSEG_+s)*FREQ_+f)*H_ + h;
    stb(sR, idx, 0.25f*ar);
    stb(sI, idx, 0.25f*ai);
  }
}

// =================== Kernel 2: gating weight ===================
__global__ __launch_bounds__(256) void k_w(const bf16* __restrict__ sR, const bf16* __restrict__ sI,
                                           const float* __restrict__ cw, const float* __restrict__ cb,
                                           float* __restrict__ wout){
  int blk = blockIdx.x; int b = blk / NSEG_; int s = blk % NSEG_; int h = threadIdx.x;
  float acc = 0.f;
  #pragma unroll
  for(int f=0;f<FREQ_;f++){
    size_t idx = ((size_t)(b*NSEG_+s)*FREQ_+f)*H_ + h;
    float r = ldb(sR, idx), i = ldb(sI, idx);
    acc += sqrtf(r*r + i*i) * cw[(s*H_+h)*FREQ_ + f];
  }
  __shared__ float red[256];
  red[h] = acc; __syncthreads();
  for(int off=128; off>0; off>>=1){ if(h<off) red[h] += red[h+off]; __syncthreads(); }
  if(h==0) wout[b*NSEG_+s] = red[0] + cb[s] + __expf((float)(s - (NSEG_-1)));
}

// =================== Kernel 3: frequency mixer ===================
__global__ __launch_bounds__(256) void k_fm(const bf16* __restrict__ sR, const bf16* __restrict__ sI,
                                            const float* __restrict__ wv_,
                                            const float* __restrict__ w1, const float* __restrict__ bb1,
                                            const float* __restrict__ w2, const float* __restrict__ bb2,
                                            bf16* __restrict__ oR, bf16* __restrict__ oI){
  int blk = blockIdx.x; int b = blk / NSEG_; int s = blk % NSEG_; int h = threadIdx.x;
  __shared__ float2 lw1[162], lw2[162], lb1[18], lb2[9];
  for(int i=threadIdx.x; i<162; i+=256){
    lw1[i] = make_float2(w1[s*162+i], w1[4212 + s*162+i]);
    lw2[i] = make_float2(w2[s*162+i], w2[4212 + s*162+i]);
  }
  if(threadIdx.x < 18) lb1[threadIdx.x] = make_float2(bb1[s*18+threadIdx.x], bb1[468 + s*18+threadIdx.x]);
  if(threadIdx.x < 9)  lb2[threadIdx.x] = make_float2(bb2[s*9+threadIdx.x],  bb2[234 + s*9+threadIdx.x]);
  __syncthreads();

  float wv = wv_[b*NSEG_+s];
  float xr[9], xi[9];
  #pragma unroll
  for(int f=0;f<9;f++){
    size_t idx = ((size_t)(b*NSEG_+s)*FREQ_+f)*H_ + h;
    xr[f] = ldb(sR, idx)*wv; xi[f] = ldb(sI, idx)*wv;
  }
  float gr[18], gi[18];
  #pragma unroll
  for(int j=0;j<18;j++){
    float hr = lb1[j].x, hi = lb1[j].y;
    #pragma unroll
    for(int f=0;f<9;f++){
      float2 ww = lw1[f*18+j];
      hr += xr[f]*ww.x - xi[f]*ww.y;
      hi += xi[f]*ww.x + xr[f]*ww.y;
    }
    gr[j] = gelu_(hr); gi[j] = gelu_(hi);
  }
  #pragma unroll
  for(int f=0;f<9;f++){
    float orr = lb2[f].x, oii = lb2[f].y;
    #pragma unroll
    for(int j=0;j<18;j++){
      float2 ww = lw2[j*9+f];
      orr += gr[j]*ww.x - gi[j]*ww.y;
      oii += gi[j]*ww.x + gi[j]*ww.y;   // reference bug replicated
    }
    size_t o = ((size_t)(s*B_+b)*FREQ_+f)*H_ + h;
    stb(oR, o, orr); stb(oI, o, oii);
  }
}

// =================== Kernel 4a: channel mixer layer1 (MFMA) ===================
// A = [Xr | Xi] (M=1152/half, K=512), B = B1t (N=1024) -> H = gelu(A.B + b1) bf16
__global__ __launch_bounds__(256) void k_cm1(const bf16* __restrict__ Xr, const bf16* __restrict__ Xi,
                                             const short* __restrict__ B1t, const float* __restrict__ b1bias,
                                             short* __restrict__ H, int half){
  int nt = blockIdx.x & 7, mt = (blockIdx.x >> 3) % 9, s = blockIdx.x / 72;
  int tid = threadIdx.x, lane = tid & 63, wave = tid >> 6;
  int wm = (wave & 1)*64, wn = (wave >> 1)*64;
  __shared__ short lA[128*LDK], lB[128*LDK];
  f32x4 acc[4][4];
  #pragma unroll
  for(int i=0;i<4;i++)
    #pragma unroll
    for(int j=0;j<4;j++) acc[i][j] = (f32x4){0.f,0.f,0.f,0.f};
  int rowbase = half*1152 + mt*128;
  const short* Bbase = B1t + ((size_t)(s*1024 + nt*128))*512;
  for(int k0=0; k0<512; k0+=64){
    const short* Asrc = (k0 < 256)
      ? (const short*)(Xr + ((size_t)(s*2304 + rowbase))*256 + k0)
      : (const short*)(Xi + ((size_t)(s*2304 + rowbase))*256 + (k0-256));
    stage_tile<128>(lA, Asrc, 256, tid);
    stage_tile<128>(lB, Bbase + k0, 512, tid);
    __syncthreads();
    mma_bk64(lA, lB, wm, wn, lane, acc);
    __syncthreads();
  }
  int m_l = lane & 15, quad = lane >> 4;
  #pragma unroll
  for(int i=0;i<4;i++){
    #pragma unroll
    for(int j=0;j<4;j++){
      int n = nt*128 + wn + j*16 + m_l;
      float bias = (n < 512) ? b1bias[s*512 + n] : b1bias[13312 + s*512 + (n-512)];
      #pragma unroll
      for(int r=0;r<4;r++){
        int mrow = wm + i*16 + quad*4 + r;
        float v = gelu_(acc[i][j][r] + bias);
        H[((size_t)(s*1152 + mt*128 + mrow))*1024 + n] = f2b(v);
      }
    }
  }
}

// =================== Kernel 4b: channel mixer layer2 (MFMA) ===================
// nt 0,1: Or = [Hr|Hi].B2r + b2r -> oR ; nt 2,3: Oi = Hi.B2i + b2i -> oI
__global__ __launch_bounds__(256) void k_cm2(const short* __restrict__ H,
                                             const short* __restrict__ B2r, const short* __restrict__ B2i,
                                             const float* __restrict__ b2bias,
                                             bf16* __restrict__ oR, bf16* __restrict__ oI, int half){
  int nt = blockIdx.x & 3, mt = (blockIdx.x>>2) % 9, s = blockIdx.x / 36;
  int tid = threadIdx.x, lane = tid & 63, wave = tid >> 6;
  int wm = (wave & 1)*64, wn = (wave >> 1)*64;
  bool isOi = nt >= 2;
  int n0 = (nt & 1)*128;
  int K = isOi ? 512 : 1024;
  int Aoff = isOi ? 512 : 0;
  int Bstride = isOi ? 512 : 1024;
  const short* Bb = isOi ? (B2i + ((size_t)(s*256 + n0))*512) : (B2r + ((size_t)(s*256 + n0))*1024);
  const short* Ab = H + ((size_t)(s*1152 + mt*128))*1024 + Aoff;
  __shared__ short lA[128*LDK], lB[128*LDK];
  f32x4 acc[4][4];
  #pragma unroll
  for(int i=0;i<4;i++)
    #pragma unroll
    for(int j=0;j<4;j++) acc[i][j] = (f32x4){0.f,0.f,0.f,0.f};
  for(int k0=0; k0<K; k0+=64){
    stage_tile<128>(lA, Ab + k0, 1024, tid);
    stage_tile<128>(lB, Bb + k0, Bstride, tid);
    __syncthreads();
    mma_bk64(lA, lB, wm, wn, lane, acc);
    __syncthreads();
  }
  int m_l = lane & 15, quad = lane >> 4;
  bf16* outp = isOi ? oI : oR;
  #pragma unroll
  for(int i=0;i<4;i++){
    #pragma unroll
    for(int j=0;j<4;j++){
      int n = n0 + wn + j*16 + m_l;
      float bias = b2bias[(isOi ? 6656 : 0) + s*256 + n];
      #pragma unroll
      for(int r=0;r<4;r++){
        int mrow = wm + i*16 + quad*4 + r;
        int rowg = half*1152 + mt*128 + mrow;
        stb(outp, ((size_t)rowg*NSEG_ + s)*256 + n, acc[i][j][r] + bias);
      }
    }
  }
}

// =================== Kernel 5: segment mixer ===================
__global__ __launch_bounds__(256) void k_sm(const bf16* __restrict__ iR, const bf16* __restrict__ iI,
                                            const float* __restrict__ w1, const float* __restrict__ bb1,
                                            const float* __restrict__ w2, const float* __restrict__ bb2,
                                            bf16* __restrict__ oR, bf16* __restrict__ oI){
  int bq = blockIdx.x / FREQ_; int f = blockIdx.x % FREQ_; int h = threadIdx.x;
  __shared__ float2 lw1[1352];
  __shared__ float2 lw2[1352];
  __shared__ float2 lb1[52], lb2[26];
  __shared__ unsigned xls[26][256];
  for(int i=threadIdx.x; i<1352; i+=256){
    lw1[i] = make_float2(w1[f*1352+i], w1[12168 + f*1352+i]);
    lw2[i] = make_float2(w2[f*1352+i], w2[12168 + f*1352+i]);
  }
  if(threadIdx.x < 52) lb1[threadIdx.x] = make_float2(bb1[f*52+threadIdx.x], bb1[468 + f*52+threadIdx.x]);
  if(threadIdx.x < 26) lb2[threadIdx.x] = make_float2(bb2[f*26+threadIdx.x], bb2[234 + f*26+threadIdx.x]);

  int rbase = (bq*FREQ_+f)*NSEG_;
  #pragma unroll
  for(int s=0;s<26;s++){
    size_t idx = ((size_t)(rbase + s))*256 + h;
    union{bf16 b; unsigned short u;} cr, ci; cr.b = iR[idx]; ci.b = iI[idx];
    xls[s][h] = (unsigned)cr.u | ((unsigned)ci.u << 16);
  }
  __syncthreads();

  float o_r[26], o_i[26];
  #pragma unroll
  for(int so=0;so<26;so++){ o_r[so] = lb2[so].x; o_i[so] = lb2[so].y; }

  #pragma unroll 1
  for(int j=0;j<52;j++){
    float hr = lb1[j].x, hi = lb1[j].y;
    #pragma unroll
    for(int s=0;s<26;s++){
      unsigned v = xls[s][h];
      union{unsigned short u; } ;
      union{bf16 b; unsigned short u;} c1, c2; c1.u = (unsigned short)(v & 0xFFFF); c2.u = (unsigned short)(v >> 16);
      float xr_ = __bfloat162float(c1.b);
      float xi_ = __bfloat162float(c2.b);
      float2 ww = lw1[s*52+j];
      hr += xr_*ww.x - xi_*ww.y;
      hi += xi_*ww.x + xr_*ww.y;
    }
    hr = gelu_(hr); hi = gelu_(hi);
    #pragma unroll
    for(int so=0;so<26;so++){
      float2 ww = lw2[j*26+so];
      o_r[so] += hr*ww.x - hi*ww.y;
      o_i[so] += hi*(ww.x + ww.y);   // reference bug replicated
    }
  }
  #pragma unroll
  for(int so=0;so<26;so++){
    size_t o = ((size_t)(rbase + so))*256 + h;
    stb(oR, o, o_r[so]); stb(oI, o, o_i[so]);
  }
}

// =================== Kernel 6: iSTFT + residual + LayerNorm ===================
__global__ __launch_bounds__(256) void k_ist(const bf16* __restrict__ iR, const bf16* __restrict__ iI,
                                             const float* __restrict__ inp,
                                             const float* __restrict__ lnw, const float* __restrict__ lnb,
                                             float* __restrict__ hs, bf16* __restrict__ hsb){
  int blk = blockIdx.x; int b = blk / SEQ_; int t = blk % SEQ_; int h = threadIdx.x;
  int l = t + 8;
  int s2 = l >> 3, k2 = l & 7;
  int s1 = s2 - 1, k1 = k2 + 8;
  float acc = 0.f;
  #pragma unroll
  for(int p=0;p<2;p++){
    int s = p ? s2 : s1;
    int k = p ? k2 : k1;
    size_t base = (size_t)(b*FREQ_)*NSEG_;
    float v = ldb(iR, (base + 0*NSEG_ + s)*256 + h);
    float a8 = ldb(iR, (base + 8*NSEG_ + s)*256 + h);
    v += (k & 1) ? -a8 : a8;
    #pragma unroll
    for(int f=1;f<8;f++){
      int m = (f*k) & 15;
      float rr = ldb(iR, (base + f*NSEG_ + s)*256 + h);
      float ii = ldb(iI, (base + f*NSEG_ + s)*256 + h);
      v += 2.f*(rr*CT16[m] - ii*ST16[m]);
    }
    acc += 0.25f*v;
  }
  float z = 0.5f*acc + inp[(size_t)(b*SEQ_+t)*H_ + h];

  __shared__ float red[256];
  red[h] = z; __syncthreads();
  for(int off=128; off>0; off>>=1){ if(h<off) red[h] += red[h+off]; __syncthreads(); }
  float u = red[0] * (1.f/256.f);
  __syncthreads();
  float d = z - u;
  red[h] = d*d; __syncthreads();
  for(int off=128; off>0; off>>=1){ if(h<off) red[h] += red[h+off]; __syncthreads(); }
  float var = red[0] * (1.f/256.f);
  float o = lnw[h]*d*rsqrtf(var + 1e-12f) + lnb[h];
  size_t oi = (size_t)(b*SEQ_+t)*H_ + h;
  hs[oi] = o;
  stb(hsb, oi, o);
}

// =================== Kernel 7: FFN layer1 (MFMA, 256->1024, gelu) ===================
__global__ __launch_bounds__(256) void k_ff1m(const short* __restrict__ hsb, const short* __restrict__ fw1t,
                                              const float* __restrict__ fb1, short* __restrict__ hid, int row0){
  int nt = blockIdx.x & 7, mt = blockIdx.x >> 3;      // mt 0..199
  int tid = threadIdx.x, lane = tid & 63, wave = tid >> 6;
  int wm = (wave & 1)*64, wn = (wave >> 1)*64;
  __shared__ short lA[128*LDK], lB[128*LDK];
  f32x4 acc[4][4];
  #pragma unroll
  for(int i=0;i<4;i++)
    #pragma unroll
    for(int j=0;j<4;j++) acc[i][j] = (f32x4){0.f,0.f,0.f,0.f};
  const short* Ab = hsb + ((size_t)(row0 + mt*128))*256;
  const short* Bb = fw1t + ((size_t)(nt*128))*256;
  for(int k0=0; k0<256; k0+=64){
    stage_tile<128>(lA, Ab + k0, 256, tid);
    stage_tile<128>(lB, Bb + k0, 256, tid);
    __syncthreads();
    mma_bk64(lA, lB, wm, wn, lane, acc);
    __syncthreads();
  }
  int m_l = lane & 15, quad = lane >> 4;
  #pragma unroll
  for(int i=0;i<4;i++){
    #pragma unroll
    for(int j=0;j<4;j++){
      int n = nt*128 + wn + j*16 + m_l;
      float bias = fb1[n];
      #pragma unroll
      for(int r=0;r<4;r++){
        int mrow = wm + i*16 + quad*4 + r;
        hid[((size_t)(mt*128 + mrow))*1024 + n] = f2b(gelu_(acc[i][j][r] + bias));
      }
    }
  }
}

// =================== Kernel 8: FFN layer2 (MFMA) + residual + LayerNorm ===================
// tile 64 rows x 256 cols (full N so LN completes in-block); 4 waves = 1x4 n-strips
__global__ __launch_bounds__(256) void k_ff2m(const short* __restrict__ hid, const short* __restrict__ fw2t,
                                              const float* __restrict__ fb2, const float* __restrict__ hs,
                                              const float* __restrict__ lnw, const float* __restrict__ lnb,
                                              float* __restrict__ out, int row0){
  int mt = blockIdx.x;                                 // 0..399
  int tid = threadIdx.x, lane = tid & 63, wave = tid >> 6;
  int wn = wave*64;
  __shared__ short lA[64*LDK], lB[256*LDK];
  __shared__ float ssum[64][4], ssq[64][4];
  f32x4 acc[4][4];
  #pragma unroll
  for(int i=0;i<4;i++)
    #pragma unroll
    for(int j=0;j<4;j++) acc[i][j] = (f32x4){0.f,0.f,0.f,0.f};
  const short* Ab = hid + ((size_t)(mt*64))*1024;
  for(int k0=0; k0<1024; k0+=64){
    stage_tile<64>(lA, Ab + k0, 1024, tid);
    stage_tile<256>(lB, fw2t + k0, 1024, tid);
    __syncthreads();
    mma_bk64(lA, lB, 0, wn, lane, acc);
    __syncthreads();
  }
  int m_l = lane & 15, quad = lane >> 4;
  int rowg0 = row0 + mt*64;
  // bias + residual
  #pragma unroll
  for(int i=0;i<4;i++){
    #pragma unroll
    for(int j=0;j<4;j++){
      int col = wn + j*16 + m_l;
      float bias = fb2[col];
      #pragma unroll
      for(int r=0;r<4;r++){
        int mrow = i*16 + quad*4 + r;
        acc[i][j][r] += bias + hs[(size_t)(rowg0+mrow)*256 + col];
      }
    }
  }
  // per-row stats: in-lane over j, shuffle over 16 lanes, LDS across waves
  #pragma unroll
  for(int i=0;i<4;i++){
    #pragma unroll
    for(int r=0;r<4;r++){
      float sv = 0.f, sq = 0.f;
      #pragma unroll
      for(int j=0;j<4;j++){ float v = acc[i][j][r]; sv += v; sq += v*v; }
      #pragma unroll
      for(int msk=1; msk<16; msk<<=1){ sv += __shfl_xor(sv, msk); sq += __shfl_xor(sq, msk); }
      if(m_l == 0){ int mrow = i*16 + quad*4 + r; ssum[mrow][wave] = sv; ssq[mrow][wave] = sq; }
    }
  }
  __syncthreads();
  if(tid < 64){
    float s1 = ssum[tid][0]+ssum[tid][1]+ssum[tid][2]+ssum[tid][3];
    float s2 = ssq[tid][0]+ssq[tid][1]+ssq[tid][2]+ssq[tid][3];
    float mean = s1*(1.f/256.f);
    float var  = s2*(1.f/256.f) - mean*mean;
    ssum[tid][0] = mean;
    ssq[tid][0]  = rsqrtf(var + 1e-12f);
  }
  __syncthreads();
  #pragma unroll
  for(int i=0;i<4;i++){
    #pragma unroll
    for(int j=0;j<4;j++){
      int col = wn + j*16 + m_l;
      float gw = lnw[col], gb = lnb[col];
      #pragma unroll
      for(int r=0;r<4;r++){
        int mrow = i*16 + quad*4 + r;
        float mean = ssum[mrow][0], inv = ssq[mrow][0];
        out[(size_t)(rowg0+mrow)*256 + col] = (acc[i][j][r] - mean)*inv*gw + gb;
      }
    }
  }
}

// =================== launch ===================
extern "C" void kernel_launch(void* const* d_in, const int* in_sizes, int n_in,
                              void* d_out, int out_size, void* d_ws, size_t ws_size,
                              hipStream_t stream){
  const float* inp    = (const float*)d_in[0];
  const float* conv_w = (const float*)d_in[1];
  const float* conv_b = (const float*)d_in[2];
  const float* fm_w1  = (const float*)d_in[3];
  const float* fm_b1  = (const float*)d_in[4];
  const float* fm_w2  = (const float*)d_in[5];
  const float* fm_b2  = (const float*)d_in[6];
  const float* cm_w1  = (const float*)d_in[7];
  const float* cm_b1  = (const float*)d_in[8];
  const float* cm_w2  = (const float*)d_in[9];
  const float* cm_b2  = (const float*)d_in[10];
  const float* sm_w1  = (const float*)d_in[11];
  const float* sm_b1  = (const float*)d_in[12];
  const float* sm_w2  = (const float*)d_in[13];
  const float* sm_b2  = (const float*)d_in[14];
  const float* ln_w   = (const float*)d_in[15];
  const float* ln_b   = (const float*)d_in[16];
  const float* ff_w1  = (const float*)d_in[17];
  const float* ff_b1  = (const float*)d_in[18];
  const float* ff_w2  = (const float*)d_in[19];
  const float* ff_b2  = (const float*)d_in[20];
  const float* ffln_w = (const float*)d_in[21];
  const float* ffln_b = (const float*)d_in[22];
  float* out = (float*)d_out;

  const size_t NS = (size_t)B_ * NSEG_ * FREQ_ * H_;   // 15,335,424
  const size_t HN = (size_t)NSEG_ * 1152 * 1024;       // 30,670,848
  short* ws = (short*)d_ws;
  bf16*  b0   = (bf16*)ws;                  // region A
  bf16*  b1   = (bf16*)(ws + NS);
  bf16*  b2   = (bf16*)(ws + 2*NS);         // region B
  bf16*  b3   = (bf16*)(ws + 3*NS);
  short* H    = ws + 4*NS;                  // 61.3 MB (half of 26x2304x1024)
  short* B1t  = H + HN;                     // 27.3 MB
  short* B2r  = B1t + (size_t)26*1024*512;  // 13.6 MB
  short* B2i  = B2r + (size_t)26*256*1024;  // 6.8 MB
  short* fw1t = B2i + (size_t)26*256*512;   // 0.5 MB
  short* fw2t = fw1t + 262144;              // 0.5 MB
  float* wbuf = (float*)(fw2t + 262144);
  float* hs   = (float*)b0;                 // 52.4 MB over region A (dead after k_sm)
  bf16*  hsb  = (bf16*)H;                   // 26.2 MB over H (dead after k_cm2)
  short* hid  = (short*)b2;                 // 52.4 MB over region B (dead after k_ist)

  // ---- weight repack (idempotent, every call) ----
  k_prep_b1<<<1664, 256, 0, stream>>>(cm_w1, B1t);
  k_prep_b2<<<832,  256, 0, stream>>>(cm_w2, B2r, B2i);
  k_transp <<<64,   256, 0, stream>>>(ff_w1, fw1t, 256, 1024);
  k_transp <<<64,   256, 0, stream>>>(ff_w2, fw2t, 1024, 256);

  // ---- pipeline ----
  k_stft<<<B_*NSEG_, 256, 0, stream>>>(inp, b0, b1);
  k_w   <<<B_*NSEG_, 256, 0, stream>>>(b0, b1, conv_w, conv_b, wbuf);
  k_fm  <<<B_*NSEG_, 256, 0, stream>>>(b0, b1, wbuf, fm_w1, fm_b1, fm_w2, fm_b2, b2, b3);
  for(int half=0; half<2; half++){
    k_cm1<<<26*72, 256, 0, stream>>>(b2, b3, B1t, cm_b1, H, half);
    k_cm2<<<26*36, 256, 0, stream>>>(H, B2r, B2i, cm_b2, b0, b1, half);
  }
  k_sm <<<B_*FREQ_, 256, 0, stream>>>(b0, b1, sm_w1, sm_b1, sm_w2, sm_b2, b2, b3);
  k_ist<<<B_*SEQ_,  256, 0, stream>>>(b2, b3, inp, ln_w, ln_b, hs, hsb);
  for(int c=0; c<2; c++){
    int row0 = c*25600;
    k_ff1m<<<1600, 256, 0, stream>>>((const short*)hsb, fw1t, ff_b1, hid, row0);
    k_ff2m<<<400,  256, 0, stream>>>(hid, fw2t, ff_b2, hs, ffln_w, ffln_b, out, row0);
  }
}